// Round 7
// baseline (297.368 us; speedup 1.0000x reference)
//
#include <hip/hip_runtime.h>
#include <hip/hip_bf16.h>

using bf16 = __hip_bfloat16;
typedef __attribute__((ext_vector_type(8))) __bf16 bf16x8;
typedef __attribute__((ext_vector_type(4))) __bf16 bf16x4;
typedef __attribute__((ext_vector_type(4))) float floatx4;

#define B_  16
#define T_  1024
#define C_  768
#define M_  16384  // B_*T_

#define OFF_XK ((size_t)0)
#define OFF_XV ((size_t)25165824)
#define OFF_XR ((size_t)50331648)
#define OFF_K  ((size_t)75497472)
#define OFF_V  ((size_t)100663296)
#define OFF_SR ((size_t)125829120)
#define OFF_WT ((size_t)150994944)
#define OFF_Y  ((size_t)0)          // bf16 y[bt][c] aliases xk (dead after mix3)
#define OFF_Z  ((size_t)50331648)   // bf16 z aliases xr (dead after mix3)

struct __align__(16) BV8 { bf16 v[8]; };

// ================= prep: transpose_w + shift_mix merged =================
__global__ __launch_bounds__(256) void prep_kernel(
    const float* __restrict__ x,
    const float* __restrict__ mk, const float* __restrict__ mv, const float* __restrict__ mr,
    const float* __restrict__ w0, const float* __restrict__ w1,
    const float* __restrict__ w2, const float* __restrict__ w3,
    bf16* __restrict__ xk, bf16* __restrict__ xv, bf16* __restrict__ xr,
    bf16* __restrict__ wt) {
  __shared__ float tile[32 * 33];
  int bid = blockIdx.x;
  if (bid < 6144) {
    int gid = bid * 256 + threadIdx.x;
    int c8 = gid % 96;
    int bt = gid / 96;
    int b  = bt >> 10;
    int t  = bt & 1023;
    int hh = t >> 5, ww = t & 31;
    int c0 = c8 * 8;
    int g  = c8 / 24;
    int sh = hh, sw = ww;
    bool valid;
    if (g == 0)      { sw = ww - 1; valid = (ww >= 1);  }
    else if (g == 1) { sw = ww + 1; valid = (ww <= 30); }
    else if (g == 2) { sh = hh - 1; valid = (hh >= 1);  }
    else             { sh = hh + 1; valid = (hh <= 30); }
    size_t off = (size_t)bt * C_ + c0;
    float xs[8], ss[8];
    *(float4*)(xs)     = *(const float4*)(x + off);
    *(float4*)(xs + 4) = *(const float4*)(x + off + 4);
    if (valid) {
      size_t soff = (size_t)(b * 1024 + sh * 32 + sw) * C_ + c0;
      *(float4*)(ss)     = *(const float4*)(x + soff);
      *(float4*)(ss + 4) = *(const float4*)(x + soff + 4);
    } else {
#pragma unroll
      for (int j = 0; j < 8; j++) ss[j] = 0.f;
    }
    BV8 ok, ov, orr;
#pragma unroll
    for (int j = 0; j < 8; j++) {
      float xf = xs[j], sf = ss[j];
      float a  = mk[c0 + j];
      float bm = mv[c0 + j];
      float cm = mr[c0 + j];
      ok.v[j]  = __float2bfloat16(xf * a  + sf * (1.f - a));
      ov.v[j]  = __float2bfloat16(xf * bm + sf * (1.f - bm));
      orr.v[j] = __float2bfloat16(xf * cm + sf * (1.f - cm));
    }
    *(BV8*)(xk + off) = ok;
    *(BV8*)(xv + off) = ov;
    *(BV8*)(xr + off) = orr;
  } else {
    int tb = bid - 6144;
    int which = tb / 576;
    int rem   = tb % 576;
    int by = rem / 24, bx = rem % 24;
    const float* src = which == 0 ? w0 : which == 1 ? w1 : which == 2 ? w2 : w3;
    bf16* dst = wt + (size_t)which * (C_ * C_);
    int k0 = by * 32;
    int n0 = bx * 32;
    int j  = threadIdx.x & 31;
    int i0 = threadIdx.x >> 5;
#pragma unroll
    for (int s = 0; s < 4; s++) {
      int i = i0 + s * 8;
      tile[i * 33 + j] = src[(size_t)(k0 + i) * C_ + n0 + j];
    }
    __syncthreads();
#pragma unroll
    for (int s = 0; s < 4; s++) {
      int i = i0 + s * 8;
      dst[(size_t)(n0 + i) * C_ + k0 + j] = __float2bfloat16(tile[j * 33 + i]);
    }
  }
}

// ---- shared GEMM body: 128x128 tile, BK=64 as two BK=32 panels ----
// Runtime mode: 1 = bf16 store, 2 = sigmoid->bf16, 3 = fp32 store.
__device__ __forceinline__ void gemm_body(
    const bf16* __restrict__ A, const bf16* __restrict__ BT,
    void* __restrict__ Cout, int M, int N, int K,
    int bx, int by, int mode) {
  __shared__ bf16 As[128 * 64];
  __shared__ bf16 Bs[128 * 64];
  int tid  = threadIdx.x;
  int wave = tid >> 6, lane = tid & 63;
  int wm = (wave & 1) * 64, wn = (wave >> 1) * 64;
  size_t m0 = (size_t)by * 128, n0 = (size_t)bx * 128;

  floatx4 acc[4][4];
#pragma unroll
  for (int i = 0; i < 4; i++)
#pragma unroll
    for (int j = 0; j < 4; j++) acc[i][j] = (floatx4){0.f, 0.f, 0.f, 0.f};

  int srow[4], skk[4];
#pragma unroll
  for (int i = 0; i < 4; i++) {
    srow[i] = ((tid >> 2) + i * 64) & 127;
    skk[i]  = (tid & 3) * 8 + (i >> 1) * 32;
  }
  bf16* lA = As + tid * 8;
  bf16* lB = Bs + tid * 8;
  int fr  = lane & 15;
  int fko = (lane >> 4) * 8;

  for (int k0 = 0; k0 < K; k0 += 64) {
#pragma unroll
    for (int i = 0; i < 4; i++) {
      __builtin_amdgcn_global_load_lds(
          (const __attribute__((address_space(1))) void*)(A + (m0 + srow[i]) * (size_t)K + k0 + skk[i]),
          (__attribute__((address_space(3))) void*)(lA + i * 2048), 16, 0, 0);
      __builtin_amdgcn_global_load_lds(
          (const __attribute__((address_space(1))) void*)(BT + (n0 + srow[i]) * (size_t)K + k0 + skk[i]),
          (__attribute__((address_space(3))) void*)(lB + i * 2048), 16, 0, 0);
    }
    __syncthreads();
#pragma unroll
    for (int s = 0; s < 2; s++) {
      bf16x8 af[4], bfr[4];
#pragma unroll
      for (int mi = 0; mi < 4; mi++)
        af[mi] = *(const bf16x8*)(As + s * 4096 + (wm + mi * 16 + fr) * 32 + fko);
#pragma unroll
      for (int ni = 0; ni < 4; ni++)
        bfr[ni] = *(const bf16x8*)(Bs + s * 4096 + (wn + ni * 16 + fr) * 32 + fko);
#pragma unroll
      for (int mi = 0; mi < 4; mi++)
#pragma unroll
        for (int ni = 0; ni < 4; ni++)
          acc[mi][ni] = __builtin_amdgcn_mfma_f32_16x16x32_bf16(
              af[mi], bfr[ni], acc[mi][ni], 0, 0, 0);
    }
    __syncthreads();
  }
  int cr = (lane >> 4) * 4;
  int cc = lane & 15;
#pragma unroll
  for (int mi = 0; mi < 4; mi++)
#pragma unroll
    for (int ni = 0; ni < 4; ni++)
#pragma unroll
      for (int i = 0; i < 4; i++) {
        size_t r   = m0 + wm + mi * 16 + cr + i;
        size_t col = n0 + wn + ni * 16 + cc;
        float val = acc[mi][ni][i];
        if (mode == 3) {
          ((float*)Cout)[r * N + col] = val;
        } else {
          if (mode == 2) val = 1.0f / (1.0f + __expf(-val));
          ((bf16*)Cout)[r * N + col] = __float2bfloat16(val);
        }
      }
}

// merged k^T / v^T / sr GEMM: z selects operands; z==2 swaps grid axes
__global__ __launch_bounds__(256, 2) void gemm_mix3(
    const bf16* __restrict__ WkT, const bf16* __restrict__ xk, bf16* __restrict__ kT,
    const bf16* __restrict__ WvT, const bf16* __restrict__ xv, bf16* __restrict__ vT,
    const bf16* __restrict__ xr,  const bf16* __restrict__ WrT, bf16* __restrict__ sr) {
  int z = blockIdx.z;
  if (z == 0)
    gemm_body(WkT, xk, kT, C_, M_, C_, blockIdx.x, blockIdx.y, 1);
  else if (z == 1)
    gemm_body(WvT, xv, vT, C_, M_, C_, blockIdx.x, blockIdx.y, 1);
  else
    gemm_body(xr, WrT, sr, M_, C_, C_, blockIdx.y, blockIdx.x, 2);
}

__global__ __launch_bounds__(256, 2) void gemm_out(
    const bf16* __restrict__ A, const bf16* __restrict__ BT,
    float* __restrict__ Cout) {
  gemm_body(A, BT, Cout, M_, C_, C_, blockIdx.x, blockIdx.y, 3);
}

// ================= WKV chunked scan, y out [bt][c] bf16 =================
// LDS-staged output: register y -> ytile[8c][1032] -> 16B-granule global writes
#define SEG 32
#define SL  32
__global__ __launch_bounds__(256) void wkv_chunked(
    const bf16* __restrict__ kT, const bf16* __restrict__ vT,
    const float* __restrict__ sd, const float* __restrict__ sf,
    bf16* __restrict__ y) {
  int tid = threadIdx.x;
  int s = tid >> 3, cr = tid & 7;
  int b = blockIdx.x / 96, cg = blockIdx.x % 96;
  int c = cg * 8 + cr;
  float w = sd[c] * (1.0f / (float)T_);
  float u = sf[c] * (1.0f / (float)T_);
  size_t base = (size_t)c * M_ + b * T_ + s * SL;
  BV8 kv[4], vv8[4];
#pragma unroll
  for (int j = 0; j < 4; j++) {
    kv[j]  = *(const BV8*)(kT + base + j * 8);
    vv8[j] = *(const BV8*)(vT + base + j * 8);
  }
  // phase 1: per-segment summary from identity
  float P = 0.f, Q = 0.f, O = -1e38f;
#pragma unroll
  for (int j = 0; j < 4; j++)
#pragma unroll
    for (int i = 0; i < 8; i++) {
      float kt = __bfloat162float(kv[j].v[i]);
      float vt = __bfloat162float(vv8[j].v[i]);
      float wo = w + O;
      float no = fmaxf(wo, kt);
      float A  = __expf(wo - no);
      float Bx = __expf(kt - no);
      P = A * P + Bx * vt;
      Q = A * Q + Bx;
      O = no;
    }
  __shared__ float sP[SEG][8], sQ[SEG][8], sO[SEG][8];
  sP[s][cr] = P; sQ[s][cr] = Q; sO[s][cr] = O;
  __syncthreads();
  // phase 2: exclusive scan across segments
  if (s == 0) {
    float p = 0.f, q = 0.f, o = -1e38f;
    float dw = (float)SL * w;
#pragma unroll 1
    for (int t = 0; t < SEG; t++) {
      float Pp = sP[t][cr], Qq = sQ[t][cr], Oo = sO[t][cr];
      sP[t][cr] = p; sQ[t][cr] = q; sO[t][cr] = o;
      float a  = dw + o;
      float no = fmaxf(a, Oo);
      float e1 = __expf(a - no);
      float e2 = __expf(Oo - no);
      p = e1 * p + e2 * Pp;
      q = e1 * q + e2 * Qq;
      o = no;
    }
  }
  __syncthreads();
  float p = sP[s][cr], q = sQ[s][cr], o = sO[s][cr];
  // phase 3: replay with true state, keep y in registers
  BV8 yo[4];
#pragma unroll
  for (int j = 0; j < 4; j++)
#pragma unroll
    for (int i = 0; i < 8; i++) {
      float kt = __bfloat162float(kv[j].v[i]);
      float vt = __bfloat162float(vv8[j].v[i]);
      float uk = u + kt;
      float no = fmaxf(o, uk);
      float A  = __expf(o - no);
      float Bx = __expf(uk - no);
      yo[j].v[i] = __float2bfloat16(__fdividef(A * p + Bx * vt, A * q + Bx));
      float wo  = w + o;
      float no2 = fmaxf(wo, kt);
      float A2 = __expf(wo - no2);
      float B2 = __expf(kt - no2);
      p = A2 * p + B2 * vt;
      q = A2 * q + B2;
      o = no2;
    }
  // stage to LDS: ytile[c][t], row stride 1032 (2-way-free b128 writes)
  __shared__ bf16 ytile[8 * 1032];
  bf16* yt = ytile + cr * 1032 + s * SL;
#pragma unroll
  for (int j = 0; j < 4; j++) *(BV8*)(yt + j * 8) = yo[j];
  __syncthreads();
  // writeback: each thread 4 tokens x 16B (8 channels)
  size_t gbase = (size_t)(b * T_) * C_ + cg * 8;
#pragma unroll
  for (int r = 0; r < 4; r++) {
    int t = tid + r * 256;
    BV8 ov;
#pragma unroll
    for (int c2 = 0; c2 < 8; c2++) ov.v[c2] = ytile[c2 * 1032 + t];
    *(BV8*)(y + gbase + (size_t)t * C_) = ov;
  }
}

// ================= LayerNorm(y)*sr -> z (bf16): one wave per row =================
__global__ __launch_bounds__(256) void ln_sr_kernel(
    const bf16* __restrict__ y, const bf16* __restrict__ sr,
    const float* __restrict__ gg, const float* __restrict__ bb,
    bf16* __restrict__ z) {
  int w = threadIdx.x >> 6, lane = threadIdx.x & 63;
  int row = blockIdx.x * 4 + w;
  size_t base = (size_t)row * C_;
  bf16x8 ya = *(const bf16x8*)(y + base + lane * 8);
  bf16x4 yb = *(const bf16x4*)(y + base + 512 + lane * 4);
  float v[12];
#pragma unroll
  for (int j = 0; j < 8; j++) v[j] = (float)ya[j];
#pragma unroll
  for (int j = 0; j < 4; j++) v[8 + j] = (float)yb[j];
  float s = 0.f, s2 = 0.f;
#pragma unroll
  for (int j = 0; j < 12; j++) { s += v[j]; s2 += v[j] * v[j]; }
#pragma unroll
  for (int off = 32; off > 0; off >>= 1) {
    s  += __shfl_xor(s, off);
    s2 += __shfl_xor(s2, off);
  }
  float mu  = s * (1.0f / (float)C_);
  float var = s2 * (1.0f / (float)C_) - mu * mu;
  float rs  = rsqrtf(var + 1e-5f);

  bf16x8 sa = *(const bf16x8*)(sr + base + lane * 8);
  bf16x4 sb = *(const bf16x4*)(sr + base + 512 + lane * 4);
  float4 g0 = *(const float4*)(gg + lane * 8);
  float4 g1 = *(const float4*)(gg + lane * 8 + 4);
  float4 g2 = *(const float4*)(gg + 512 + lane * 4);
  float4 b0 = *(const float4*)(bb + lane * 8);
  float4 b1 = *(const float4*)(bb + lane * 8 + 4);
  float4 b2 = *(const float4*)(bb + 512 + lane * 4);
  float gf[12] = {g0.x, g0.y, g0.z, g0.w, g1.x, g1.y, g1.z, g1.w,
                  g2.x, g2.y, g2.z, g2.w};
  float bf_[12] = {b0.x, b0.y, b0.z, b0.w, b1.x, b1.y, b1.z, b1.w,
                   b2.x, b2.y, b2.z, b2.w};
  float sf_[12];
#pragma unroll
  for (int j = 0; j < 8; j++) sf_[j] = (float)sa[j];
#pragma unroll
  for (int j = 0; j < 4; j++) sf_[8 + j] = (float)sb[j];
  bf16x8 za;
  bf16x4 zb;
#pragma unroll
  for (int j = 0; j < 8; j++)
    za[j] = (__bf16)(((v[j] - mu) * rs * gf[j] + bf_[j]) * sf_[j]);
#pragma unroll
  for (int j = 0; j < 4; j++)
    zb[j] = (__bf16)(((v[8 + j] - mu) * rs * gf[8 + j] + bf_[8 + j]) * sf_[8 + j]);
  *(bf16x8*)(z + base + lane * 8) = za;
  *(bf16x4*)(z + base + 512 + lane * 4) = zb;
}

extern "C" void kernel_launch(void* const* d_in, const int* in_sizes, int n_in,
                              void* d_out, int out_size, void* d_ws, size_t ws_size,
                              hipStream_t stream) {
  const float* x  = (const float*)d_in[0];
  const float* sd = (const float*)d_in[3];
  const float* sf = (const float*)d_in[4];
  const float* mk = (const float*)d_in[5];
  const float* mv = (const float*)d_in[6];
  const float* mr = (const float*)d_in[7];
  const float* Wk = (const float*)d_in[8];
  const float* Wv = (const float*)d_in[9];
  const float* Wr = (const float*)d_in[10];
  const float* Wo = (const float*)d_in[11];
  const float* lg = (const float*)d_in[12];
  const float* lb = (const float*)d_in[13];

  char* ws = (char*)d_ws;
  bf16* xk  = (bf16*)(ws + OFF_XK);
  bf16* xv  = (bf16*)(ws + OFF_XV);
  bf16* xr  = (bf16*)(ws + OFF_XR);
  bf16* kTb = (bf16*)(ws + OFF_K);
  bf16* vTb = (bf16*)(ws + OFF_V);
  bf16* srb = (bf16*)(ws + OFF_SR);
  bf16* wt  = (bf16*)(ws + OFF_WT);
  bf16* WkT = wt;
  bf16* WvT = wt + (size_t)C_ * C_;
  bf16* WrT = wt + (size_t)2 * C_ * C_;
  bf16* WoT = wt + (size_t)3 * C_ * C_;
  bf16* yb  = (bf16*)(ws + OFF_Y);
  bf16* zb  = (bf16*)(ws + OFF_Z);

  prep_kernel<<<8448, 256, 0, stream>>>(x, mk, mv, mr, Wk, Wv, Wr, Wo,
                                        xk, xv, xr, wt);

  gemm_mix3<<<dim3(M_ / 128, C_ / 128, 3), 256, 0, stream>>>(
      WkT, xk, kTb, WvT, xv, vTb, xr, WrT, srb);

  wkv_chunked<<<B_ * 96, 256, 0, stream>>>(kTb, vTb, sd, sf, yb);
  ln_sr_kernel<<<M_ / 4, 256, 0, stream>>>(yb, srb, lg, lb, zb);

  gemm_out<<<dim3(C_ / 128, M_ / 128), 256, 0, stream>>>(zb, WoT, (float*)d_out);
}